// Round 7
// baseline (92.883 us; speedup 1.0000x reference)
//
#include <hip/hip_runtime.h>
#include <math.h>

#define EDIM 128
#define NATOM 128
#define NBATCH 512
#define ROWLEN 257

typedef __attribute__((ext_vector_type(8))) short bf16x8;           // 8 bf16 (4 VGPRs)
typedef __attribute__((ext_vector_type(4))) float f32x4;            // MFMA C/D frag
typedef __attribute__((ext_vector_type(4))) unsigned short u16x4;   // 8B packed bf16
typedef float f4u __attribute__((ext_vector_type(4), aligned(4)));  // element-aligned float4

__device__ __forceinline__ unsigned short f2bf(float f) {       // RNE float->bf16
    unsigned u = __float_as_uint(f);
    u += 0x7FFFu + ((u >> 16) & 1u);
    return (unsigned short)(u >> 16);
}
__device__ __forceinline__ float bf2f(unsigned short h) {
    return __uint_as_float(((unsigned)h) << 16);
}
__device__ __forceinline__ float fast_ssp(float x) {            // softplus(x)-log2, stable
    return fmaxf(x, 0.f) + __logf(1.f + __expf(-fabsf(x))) - 0.69314718055994531f;
}
// XOR swizzle on a row-major [128][256B] bf16 plane; phase decorrelates X vs K plane.
__device__ __forceinline__ int swzp(int row, int cbyte, int phase) {
    return row * 256 + ((cbyte ^ phase) ^ ((row & 7) << 4));
}

#define PH 0
#define QH 32768
#define PLANE_SZ 65536

// d_ws element offsets (unsigned short units)
#define WS_X 65536                               // after 128KB W hi/lo split
#define WS_K (65536 + NBATCH * NATOM * EDIM)     // + 8388608

__global__ void wsplit_kernel(const float* __restrict__ Wx,
                              const float* __restrict__ Wk,
                              unsigned short* __restrict__ ws) {
    int g = blockIdx.x * 256 + threadIdx.x;          // 0..32767
    const float* src = (g < 16384) ? Wx : Wk;
    int idx = g & 16383;
    float v = src[idx];
    unsigned short h = f2bf(v);
    unsigned short l = f2bf(v - bf2f(h));
    int base = (g < 16384) ? 0 : 32768;
    ws[base + idx] = h;
    ws[base + 16384 + idx] = l;
}

// ===================== split path: k1 = activations + linear layers =====================
// 1 block = 1 batch, 512 threads (8 waves), 64KB dynamic LDS -> 2 blocks/CU.
// Writes X,K as bf16 [atom][feat] to d_ws. No masking of activations: masked-row
// garbage is finite and killed downstream (pair guards / count gates in k2).
__global__ void __launch_bounds__(512, 4)
k1_act_gemm(const float* __restrict__ kx,
            const float* __restrict__ mask,
            const float* __restrict__ bx,
            const float* __restrict__ bk,
            unsigned short* __restrict__ ws)
{
    extern __shared__ char lds[];        // act_x plane (32KB) + act_k plane (32KB)
    __shared__ int cntBs[2];
    const int b = blockIdx.x;
    const int t = threadIdx.x;
    const int lane = t & 63;
    const int w = t >> 6;                // 0..7
    const int wc = w & 3;                // atom tile (shared by both positions)
    const int wrb = w >> 2;              // 0..1 -> feature tiles wrb, wrb+2
    const int l15 = lane & 15;
    const int l4  = lane >> 4;

    // kx prefetch: 4 threads/row, 64 consecutive floats each (issues at entry)
    const int pi = t >> 2, pq = t & 3;
    const float* prow = kx + (size_t)b * (NATOM * ROWLEN) + pi * ROWLEN + pq * 64;
    f4u v[16];
    #pragma unroll
    for (int j4 = 0; j4 < 16; ++j4) v[j4] = *(const f4u*)(prow + j4 * 4);

    if (t < NATOM) {                     // count (overlaps loads)
        float m = mask[b * NATOM + t];
        unsigned long long bal = __ballot(m > 0.5f);
        if ((t & 63) == 0) cntBs[t >> 6] = __popcll(bal);
    }

    {   // activations -> swizzled bf16 planes
        const bool isX = (pq < 2);
        char* base = lds + (isX ? PH : QH);
        const int phase = isX ? 0 : 64;
        const int ebase = (pq & 1) * 64;
        #pragma unroll
        for (int j4 = 0; j4 < 16; ++j4) {
            u16x4 hs;
            #pragma unroll
            for (int c = 0; c < 4; ++c) {
                float a = isX ? fast_ssp(v[j4][c]) : fmaxf(v[j4][c], 0.f);
                hs[c] = f2bf(a);
            }
            *(u16x4*)(base + swzp(pi, (ebase + j4 * 4) * 2, phase)) = hs;
        }
    }
    __syncthreads();                     // only barrier in k1
    const int count = cntBs[0] + cntBs[1];
    const int n0 = wc * 32;
    if (n0 >= count) return;             // wave-uniform exit (no barriers after)

    #pragma unroll
    for (int mat = 0; mat < 2; ++mat) {
        const char* act = lds + (mat ? QH : PH);
        const int phase = mat ? 64 : 0;
        const unsigned short* WH = ws + mat * 32768;
        const unsigned short* WL = WH + 16384;
        const float* bias = mat ? bk : bx;
        unsigned short* dstb = ws + (mat ? WS_K : WS_X) + (size_t)b * (NATOM * EDIM);
        f32x4 acc[2][2][2] = {};         // [pos][mf][nf]
        for (int ks = 0; ks < 4; ++ks) {
            const int e0 = ks * 32 + l4 * 8;
            bf16x8 ah[2];
            #pragma unroll
            for (int nf = 0; nf < 2; ++nf)
                ah[nf] = *(const bf16x8*)(act + swzp(n0 + nf * 16 + l15, e0 * 2, phase));
            #pragma unroll
            for (int p = 0; p < 2; ++p) {
                const int wr = wrb + 2 * p;
                #pragma unroll
                for (int mf = 0; mf < 2; ++mf) {
                    int orow = wr * 32 + mf * 16 + l15;
                    bf16x8 wh = *(const bf16x8*)(WH + orow * 128 + e0);
                    bf16x8 wl = *(const bf16x8*)(WL + orow * 128 + e0);
                    #pragma unroll
                    for (int nf = 0; nf < 2; ++nf) {
                        acc[p][mf][nf] = __builtin_amdgcn_mfma_f32_16x16x32_bf16(wh, ah[nf], acc[p][mf][nf], 0, 0, 0);
                        acc[p][mf][nf] = __builtin_amdgcn_mfma_f32_16x16x32_bf16(wl, ah[nf], acc[p][mf][nf], 0, 0, 0);
                    }
                }
            }
        }
        // store tiles: X/K[b][atom][feat], 8B per lane-store
        #pragma unroll
        for (int p = 0; p < 2; ++p) {
            const int wr = wrb + 2 * p;
            #pragma unroll
            for (int mf = 0; mf < 2; ++mf) {
                int ob = wr * 32 + mf * 16 + l4 * 4;
                f32x4 b4 = *(const f32x4*)(bias + ob);
                #pragma unroll
                for (int nf = 0; nf < 2; ++nf) {
                    int jrow = n0 + nf * 16 + l15;
                    u16x4 hs;
                    #pragma unroll
                    for (int r = 0; r < 4; ++r) hs[r] = f2bf(acc[p][mf][nf][r] + b4[r]);
                    *(u16x4*)(dstb + jrow * EDIM + ob) = hs;
                }
            }
        }
    }
}

// ===================== split path: k2 = grams + pairwise epilogue + outputs =============
// 1 block = 1 batch, 512 threads, ~2.6KB LDS. X,K fragments read directly from
// global (L2/L3-hot; no LDS staging).
__global__ void __launch_bounds__(512, 4)
k2_gram_epi(const float* __restrict__ kx,
            const float* __restrict__ pos,
            const float* __restrict__ mask,
            const float* __restrict__ scale_ptr,
            const float* __restrict__ evala,
            const unsigned short* __restrict__ ws,
            float* __restrict__ out)
{
    __shared__ float posXs[NATOM], posYs[NATOM], posZs[NATOM], lsBs[NATOM];
    __shared__ float amBs[NATOM * 3];
    __shared__ float redBs[2];
    __shared__ int   cntBs[2];
    const int b = blockIdx.x;
    const int t = threadIdx.x;
    const int lane = t & 63;
    const int w = t >> 6;                // 0..7
    const int wc = w & 3;
    const int wrb = w >> 2;
    const int l15 = lane & 15;
    const int l4  = lane >> 4;

    if (t < NATOM) {
        float m = mask[b * NATOM + t];
        unsigned long long bal = __ballot(m > 0.5f);
        if ((t & 63) == 0) cntBs[t >> 6] = __popcll(bal);
        const float* p = pos + ((size_t)b * NATOM + t) * 3;
        posXs[t] = p[0]; posYs[t] = p[1]; posZs[t] = p[2];
        lsBs[t] = kx[(size_t)b * (NATOM * ROWLEN) + t * ROWLEN + 2 * EDIM];
    }
    if (t < NATOM * 3) amBs[t] = 0.f;
    __syncthreads();
    const int count = cntBs[0] + cntBs[1];
    const unsigned short* Xb = ws + WS_X + (size_t)b * (NATOM * EDIM);
    const unsigned short* Kb = ws + WS_K + (size_t)b * (NATOM * EDIM);
    const int n0g = wc * 32;

    #pragma unroll
    for (int p = 0; p < 2; ++p) {
        const int wr = wrb + 2 * p;
        const int m0g = wr * 32;
        if (m0g < count && n0g < count) {
            f32x4 gx[2][2] = {}, gk[2][2] = {};
            for (int ks = 0; ks < 4; ++ks) {             // X gram
                const int e0 = ks * 32 + l4 * 8;
                bf16x8 aH[2], bH[2];
                #pragma unroll
                for (int mf = 0; mf < 2; ++mf)
                    aH[mf] = *(const bf16x8*)(Xb + (m0g + mf * 16 + l15) * EDIM + e0);
                #pragma unroll
                for (int nf = 0; nf < 2; ++nf)
                    bH[nf] = *(const bf16x8*)(Xb + (n0g + nf * 16 + l15) * EDIM + e0);
                #pragma unroll
                for (int mf = 0; mf < 2; ++mf)
                    #pragma unroll
                    for (int nf = 0; nf < 2; ++nf)
                        gx[mf][nf] = __builtin_amdgcn_mfma_f32_16x16x32_bf16(aH[mf], bH[nf], gx[mf][nf], 0, 0, 0);
            }
            for (int ks = 0; ks < 4; ++ks) {             // K gram
                const int e0 = ks * 32 + l4 * 8;
                bf16x8 aH[2], bH[2];
                #pragma unroll
                for (int mf = 0; mf < 2; ++mf)
                    aH[mf] = *(const bf16x8*)(Kb + (m0g + mf * 16 + l15) * EDIM + e0);
                #pragma unroll
                for (int nf = 0; nf < 2; ++nf)
                    bH[nf] = *(const bf16x8*)(Kb + (n0g + nf * 16 + l15) * EDIM + e0);
                #pragma unroll
                for (int mf = 0; mf < 2; ++mf)
                    #pragma unroll
                    for (int nf = 0; nf < 2; ++nf)
                        gk[mf][nf] = __builtin_amdgcn_mfma_f32_16x16x32_bf16(aH[mf], bH[nf], gk[mf][nf], 0, 0, 0);
            }
            const float inv_e = 0.08838834764831845f;    // 1/sqrt(128)
            #pragma unroll
            for (int nf = 0; nf < 2; ++nf) {
                const int j = n0g + nf * 16 + l15;
                const bool jvalid = (j < count);
                const float pjx = posXs[j], pjy = posYs[j], pjz = posZs[j];
                float amx = 0.f, amy = 0.f, amz = 0.f;
                #pragma unroll
                for (int mf = 0; mf < 2; ++mf) {
                    #pragma unroll
                    for (int r = 0; r < 4; ++r) {
                        const int i = m0g + mf * 16 + l4 * 4 + r;
                        float dx = pjx - posXs[i];
                        float dy = pjy - posYs[i];
                        float dz = pjz - posZs[i];
                        float r2 = fmaf(dx, dx, fmaf(dy, dy, dz * dz)) + 1e-16f;
                        float rr = sqrtf(r2);
                        bool ok = jvalid && (i < count) && (rr < 5.0f);
                        float fc = ok ? (0.5f * (__cosf(rr * 0.62831853071795865f) + 1.f)) : 0.f;
                        float xs = fmaf(gx[mf][nf][r], -0.044194173824159216f, rr * 0.5f);
                        float fv = xs * (gk[mf][nf][r] * inv_e) * fc;
                        float wgt = fv / (rr + 1e-8f);
                        amx = fmaf(dx, wgt, amx);
                        amy = fmaf(dy, wgt, amy);
                        amz = fmaf(dz, wgt, amz);
                    }
                }
                amx += __shfl_xor(amx, 16); amx += __shfl_xor(amx, 32);
                amy += __shfl_xor(amy, 16); amy += __shfl_xor(amy, 32);
                amz += __shfl_xor(amz, 16); amz += __shfl_xor(amz, 32);
                if (l4 == 0 && jvalid) {
                    atomicAdd(&amBs[j * 3 + 0], amx);
                    atomicAdd(&amBs[j * 3 + 1], amy);
                    atomicAdd(&amBs[j * 3 + 2], amz);
                }
            }
        }
    }
    __syncthreads();

    // outputs
    if (t < 96) {
        f32x4 ev4 = *(const f32x4*)(evala + (size_t)b * 384 + t * 4);
        f32x4 o4;
        #pragma unroll
        for (int c = 0; c < 4; ++c) o4[c] = ((t * 4 + c) / 3 < count) ? ev4[c] : 0.f;
        *(f32x4*)(out + (size_t)b * 384 + t * 4) = o4;
    }
    float lp = 0.f;
    if (t < NATOM && t < count) {
        const float* ev = evala + ((size_t)b * NATOM + t) * 3;
        float e0v = ev[0], e1v = ev[1], e2v = ev[2];
        float scale = scale_ptr[0];
        float ax = amBs[t * 3 + 0], ay = amBs[t * 3 + 1], az = amBs[t * 3 + 2];
        float nrm = sqrtf(fmaf(ax, ax, fmaf(ay, ay, az * az)) + 1e-16f) + 1e-8f;
        float qe = __expf(-2.f * nrm);
        float th = (1.f - qe) / (1.f + qe);
        float sc = th / nrm * scale;
        float ls = fminf(fmaxf(lsBs[t], -20.f), 2.f);
        float sig = __expf(ls) * scale;
        float sinv = 1.f / sig;
        float zx = (e0v - ax * sc) * sinv;
        float zy = (e1v - ay * sc) * sinv;
        float zz = (e2v - az * sc) * sinv;
        lp = -0.5f * (zx * zx + zy * zy + zz * zz) - 3.f * __logf(sig)
             - 3.f * 0.91893853320467274f;
    }
    #pragma unroll
    for (int off = 32; off > 0; off >>= 1) lp += __shfl_down(lp, off);
    if (t == 0)  redBs[0] = lp;
    if (t == 64) redBs[1] = lp;
    __syncthreads();
    if (t == 0) out[(size_t)NBATCH * NATOM * 3 + b] = redBs[0] + redBs[1];
}

// ===================== fallback (R6 monolithic) — used only if ws_size < 34MB ==========

__device__ __forceinline__ void act_store(char* plane, const f4u v[8], int pi, int pq) {
    const bool isX = (pq < 4);
    char* base = plane + (isX ? PH : QH);
    const int phase = isX ? 0 : 64;
    const int ebase = (pq & 3) * 32;
    #pragma unroll
    for (int j4 = 0; j4 < 8; ++j4) {
        u16x4 hs;
        #pragma unroll
        for (int c = 0; c < 4; ++c) {
            float a = isX ? fast_ssp(v[j4][c]) : fmaxf(v[j4][c], 0.f);
            hs[c] = f2bf(a);
        }
        *(u16x4*)(base + swzp(pi, (ebase + j4 * 4) * 2, phase)) = hs;
    }
}

__device__ __forceinline__ void gemm_mats(const char* plane, const unsigned short* ws,
        const float* bxp, const float* bkp, int wr, int wc, int l15, int l4,
        u16x4 xpk[2][2], u16x4 kpk[2][2], bool nact) {
    if (!nact) return;
    #pragma unroll
    for (int mat = 0; mat < 2; ++mat) {
        const char* act = plane + (mat ? QH : PH);
        const int phase = mat ? 64 : 0;
        const unsigned short* WH = ws + mat * 32768;
        const unsigned short* WL = WH + 16384;
        const float* bias = mat ? bkp : bxp;
        const int n0 = wc * 32;
        f32x4 acc[2][2] = {};
        for (int ks = 0; ks < 4; ++ks) {
            const int e0 = ks * 32 + l4 * 8;
            bf16x8 wh[2], wl[2], ah[2];
            #pragma unroll
            for (int mf = 0; mf < 2; ++mf) {
                int orow = wr * 32 + mf * 16 + l15;
                wh[mf] = *(const bf16x8*)(WH + orow * 128 + e0);
                wl[mf] = *(const bf16x8*)(WL + orow * 128 + e0);
            }
            #pragma unroll
            for (int nf = 0; nf < 2; ++nf) {
                int jrow = n0 + nf * 16 + l15;
                ah[nf] = *(const bf16x8*)(act + swzp(jrow, e0 * 2, phase));
            }
            #pragma unroll
            for (int mf = 0; mf < 2; ++mf)
                #pragma unroll
                for (int nf = 0; nf < 2; ++nf) {
                    acc[mf][nf] = __builtin_amdgcn_mfma_f32_16x16x32_bf16(wh[mf], ah[nf], acc[mf][nf], 0, 0, 0);
                    acc[mf][nf] = __builtin_amdgcn_mfma_f32_16x16x32_bf16(wl[mf], ah[nf], acc[mf][nf], 0, 0, 0);
                }
        }
        #pragma unroll
        for (int mf = 0; mf < 2; ++mf) {
            int ob = wr * 32 + mf * 16 + l4 * 4;
            f32x4 b4 = *(const f32x4*)(bias + ob);
            #pragma unroll
            for (int nf = 0; nf < 2; ++nf) {
                u16x4 hs;
                #pragma unroll
                for (int r = 0; r < 4; ++r) hs[r] = f2bf(acc[mf][nf][r] + b4[r]);
                if (mat) kpk[mf][nf] = hs; else xpk[mf][nf] = hs;
            }
        }
    }
}

__device__ __forceinline__ void write_xk(char* plane, int wr, int wc, int l15, int l4,
        const u16x4 xpk[2][2], const u16x4 kpk[2][2], bool nact) {
    if (!nact) return;
    const int n0 = wc * 32;
    #pragma unroll
    for (int mf = 0; mf < 2; ++mf) {
        int ob2 = (wr * 32 + mf * 16 + l4 * 4) * 2;
        #pragma unroll
        for (int nf = 0; nf < 2; ++nf) {
            int jrow = n0 + nf * 16 + l15;
            *(u16x4*)(plane + PH + swzp(jrow, ob2, 0))  = xpk[mf][nf];
            *(u16x4*)(plane + QH + swzp(jrow, ob2, 64)) = kpk[mf][nf];
        }
    }
}

__device__ __forceinline__ void gram_epi(const char* plane, const float* pX, const float* pY,
        const float* pZ, float* amB, int wr, int wc, int l15, int l4, int count) {
    const int m0g = wr * 32;
    const int n0g = wc * 32;
    if (m0g >= count || n0g >= count) return;
    f32x4 gx[2][2] = {}, gk[2][2] = {};
    for (int ks = 0; ks < 4; ++ks) {
        const int e0b = (ks * 32 + l4 * 8) * 2;
        bf16x8 aH[2], bH[2];
        #pragma unroll
        for (int mf = 0; mf < 2; ++mf)
            aH[mf] = *(const bf16x8*)(plane + PH + swzp(m0g + mf * 16 + l15, e0b, 0));
        #pragma unroll
        for (int nf = 0; nf < 2; ++nf)
            bH[nf] = *(const bf16x8*)(plane + PH + swzp(n0g + nf * 16 + l15, e0b, 0));
        #pragma unroll
        for (int mf = 0; mf < 2; ++mf)
            #pragma unroll
            for (int nf = 0; nf < 2; ++nf)
                gx[mf][nf] = __builtin_amdgcn_mfma_f32_16x16x32_bf16(aH[mf], bH[nf], gx[mf][nf], 0, 0, 0);
    }
    for (int ks = 0; ks < 4; ++ks) {
        const int e0b = (ks * 32 + l4 * 8) * 2;
        bf16x8 aH[2], bH[2];
        #pragma unroll
        for (int mf = 0; mf < 2; ++mf)
            aH[mf] = *(const bf16x8*)(plane + QH + swzp(m0g + mf * 16 + l15, e0b, 64));
        #pragma unroll
        for (int nf = 0; nf < 2; ++nf)
            bH[nf] = *(const bf16x8*)(plane + QH + swzp(n0g + nf * 16 + l15, e0b, 64));
        #pragma unroll
        for (int mf = 0; mf < 2; ++mf)
            #pragma unroll
            for (int nf = 0; nf < 2; ++nf)
                gk[mf][nf] = __builtin_amdgcn_mfma_f32_16x16x32_bf16(aH[mf], bH[nf], gk[mf][nf], 0, 0, 0);
    }
    const float inv_e = 0.08838834764831845f;
    #pragma unroll
    for (int nf = 0; nf < 2; ++nf) {
        const int j = n0g + nf * 16 + l15;
        const bool jvalid = (j < count);
        const float pjx = pX[j], pjy = pY[j], pjz = pZ[j];
        float amx = 0.f, amy = 0.f, amz = 0.f;
        #pragma unroll
        for (int mf = 0; mf < 2; ++mf) {
            #pragma unroll
            for (int r = 0; r < 4; ++r) {
                const int i = m0g + mf * 16 + l4 * 4 + r;
                float dx = pjx - pX[i];
                float dy = pjy - pY[i];
                float dz = pjz - pZ[i];
                float r2 = fmaf(dx, dx, fmaf(dy, dy, dz * dz)) + 1e-16f;
                float rr = sqrtf(r2);
                bool ok = jvalid && (i < count) && (rr < 5.0f);
                float fc = ok ? (0.5f * (__cosf(rr * 0.62831853071795865f) + 1.f)) : 0.f;
                float xs = fmaf(gx[mf][nf][r], -0.044194173824159216f, rr * 0.5f);
                float fv = xs * (gk[mf][nf][r] * inv_e) * fc;
                float wgt = fv / (rr + 1e-8f);
                amx = fmaf(dx, wgt, amx);
                amy = fmaf(dy, wgt, amy);
                amz = fmaf(dz, wgt, amz);
            }
        }
        amx += __shfl_xor(amx, 16); amx += __shfl_xor(amx, 32);
        amy += __shfl_xor(amy, 16); amy += __shfl_xor(amy, 32);
        amz += __shfl_xor(amz, 16); amz += __shfl_xor(amz, 32);
        if (l4 == 0 && jvalid) {
            atomicAdd(&amB[j * 3 + 0], amx);
            atomicAdd(&amB[j * 3 + 1], amy);
            atomicAdd(&amB[j * 3 + 2], amz);
        }
    }
}

__global__ void __launch_bounds__(1024, 4)
gen_actions_fallback(const float* __restrict__ kx,
                     const float* __restrict__ pos,
                     const float* __restrict__ mask,
                     const float* __restrict__ scale_ptr,
                     const float* __restrict__ evala,
                     const float* __restrict__ bx,
                     const float* __restrict__ bk,
                     const unsigned short* __restrict__ ws,
                     float* __restrict__ out)
{
    extern __shared__ char lds[];
    __shared__ float posXs[2 * NATOM], posYs[2 * NATOM], posZs[2 * NATOM];
    __shared__ float lsBs[2 * NATOM];
    __shared__ float amBs[2 * NATOM * 3];
    __shared__ float redBs[4];
    __shared__ int   cntBs[4];

    const int bA = blockIdx.x * 2;
    const int bB = bA + 1;
    const int t = threadIdx.x;
    const int lane = t & 63;
    const int w = t >> 6;
    const int wr = w >> 2;
    const int wc = w & 3;
    const int l15 = lane & 15;
    const int l4  = lane >> 4;
    char* planeA = lds;
    char* planeB = lds + PLANE_SZ;

    const int pi = t >> 3, pq = t & 7;
    const float* prowA = kx + (size_t)bA * (NATOM * ROWLEN) + pi * ROWLEN + pq * 32;
    const float* prowB = kx + (size_t)bB * (NATOM * ROWLEN) + pi * ROWLEN + pq * 32;
    f4u vA[8], vB[8];
    #pragma unroll
    for (int j4 = 0; j4 < 8; ++j4) vA[j4] = *(const f4u*)(prowA + j4 * 4);
    #pragma unroll
    for (int j4 = 0; j4 < 8; ++j4) vB[j4] = *(const f4u*)(prowB + j4 * 4);
    float lstdA = (pq == 7) ? prowA[32] : 0.f;
    float lstdB = (pq == 7) ? prowB[32] : 0.f;

    if (t < 2 * NATOM) {
        const int r = t & 127;
        const int bb = (t < NATOM) ? bA : bB;
        float m = mask[bb * NATOM + r];
        unsigned long long bal = __ballot(m > 0.5f);
        if (lane == 0) cntBs[w] = __popcll(bal);
        const float* p = pos + ((size_t)bb * NATOM + r) * 3;
        posXs[t] = p[0]; posYs[t] = p[1]; posZs[t] = p[2];
    }
    if (t < 2 * NATOM * 3) amBs[t] = 0.f;

    act_store(planeA, vA, pi, pq);
    if (pq == 7) { lsBs[pi] = lstdA; lsBs[NATOM + pi] = lstdB; }
    __syncthreads();
    const int countA = cntBs[0] + cntBs[1];
    const int countB = cntBs[2] + cntBs[3];
    const bool nactA = (wc * 32 < countA);
    const bool nactB = (wc * 32 < countB);

    u16x4 xpkA[2][2], kpkA[2][2];
    gemm_mats(planeA, ws, bx, bk, wr, wc, l15, l4, xpkA, kpkA, nactA);
    __syncthreads();
    write_xk(planeA, wr, wc, l15, l4, xpkA, kpkA, nactA);
    act_store(planeB, vB, pi, pq);
    __syncthreads();

    gram_epi(planeA, posXs, posYs, posZs, amBs, wr, wc, l15, l4, countA);
    u16x4 xpkB[2][2], kpkB[2][2];
    gemm_mats(planeB, ws, bx, bk, wr, wc, l15, l4, xpkB, kpkB, nactB);
    __syncthreads();
    write_xk(planeB, wr, wc, l15, l4, xpkB, kpkB, nactB);

    if (t < 96) {
        f32x4 ev4 = *(const f32x4*)(evala + (size_t)bA * 384 + t * 4);
        f32x4 o4;
        #pragma unroll
        for (int c = 0; c < 4; ++c) o4[c] = ((t * 4 + c) / 3 < countA) ? ev4[c] : 0.f;
        *(f32x4*)(out + (size_t)bA * 384 + t * 4) = o4;
    }
    {
        float lp = 0.f;
        if (t < NATOM && t < countA) {
            const float* ev = evala + ((size_t)bA * NATOM + t) * 3;
            float e0v = ev[0], e1v = ev[1], e2v = ev[2];
            float scale = scale_ptr[0];
            float ax = amBs[t * 3 + 0], ay = amBs[t * 3 + 1], az = amBs[t * 3 + 2];
            float nrm = sqrtf(fmaf(ax, ax, fmaf(ay, ay, az * az)) + 1e-16f) + 1e-8f;
            float qe = __expf(-2.f * nrm);
            float th = (1.f - qe) / (1.f + qe);
            float sc = th / nrm * scale;
            float ls = fminf(fmaxf(lsBs[t], -20.f), 2.f);
            float sig = __expf(ls) * scale;
            float sinv = 1.f / sig;
            float zx = (e0v - ax * sc) * sinv;
            float zy = (e1v - ay * sc) * sinv;
            float zz = (e2v - az * sc) * sinv;
            lp = -0.5f * (zx * zx + zy * zy + zz * zz) - 3.f * __logf(sig)
                 - 3.f * 0.91893853320467274f;
        }
        #pragma unroll
        for (int off = 32; off > 0; off >>= 1) lp += __shfl_down(lp, off);
        if (t == 0)  redBs[0] = lp;
        if (t == 64) redBs[1] = lp;
    }
    __syncthreads();

    gram_epi(planeB, posXs + NATOM, posYs + NATOM, posZs + NATOM,
             amBs + NATOM * 3, wr, wc, l15, l4, countB);
    if (t == 0) out[(size_t)NBATCH * NATOM * 3 + bA] = redBs[0] + redBs[1];
    __syncthreads();

    if (t < 96) {
        f32x4 ev4 = *(const f32x4*)(evala + (size_t)bB * 384 + t * 4);
        f32x4 o4;
        #pragma unroll
        for (int c = 0; c < 4; ++c) o4[c] = ((t * 4 + c) / 3 < countB) ? ev4[c] : 0.f;
        *(f32x4*)(out + (size_t)bB * 384 + t * 4) = o4;
    }
    {
        float lp = 0.f;
        if (t < NATOM && t < countB) {
            const float* ev = evala + ((size_t)bB * NATOM + t) * 3;
            float e0v = ev[0], e1v = ev[1], e2v = ev[2];
            float scale = scale_ptr[0];
            float ax = amBs[NATOM * 3 + t * 3 + 0];
            float ay = amBs[NATOM * 3 + t * 3 + 1];
            float az = amBs[NATOM * 3 + t * 3 + 2];
            float nrm = sqrtf(fmaf(ax, ax, fmaf(ay, ay, az * az)) + 1e-16f) + 1e-8f;
            float qe = __expf(-2.f * nrm);
            float th = (1.f - qe) / (1.f + qe);
            float sc = th / nrm * scale;
            float ls = fminf(fmaxf(lsBs[NATOM + t], -20.f), 2.f);
            float sig = __expf(ls) * scale;
            float sinv = 1.f / sig;
            float zx = (e0v - ax * sc) * sinv;
            float zy = (e1v - ay * sc) * sinv;
            float zz = (e2v - az * sc) * sinv;
            lp = -0.5f * (zx * zx + zy * zy + zz * zz) - 3.f * __logf(sig)
                 - 3.f * 0.91893853320467274f;
        }
        #pragma unroll
        for (int off = 32; off > 0; off >>= 1) lp += __shfl_down(lp, off);
        if (t == 0)  redBs[2] = lp;
        if (t == 64) redBs[3] = lp;
    }
    __syncthreads();
    if (t == 0) out[(size_t)NBATCH * NATOM * 3 + bB] = redBs[2] + redBs[3];
}

extern "C" void kernel_launch(void* const* d_in, const int* in_sizes, int n_in,
                              void* d_out, int out_size, void* d_ws, size_t ws_size,
                              hipStream_t stream) {
    const float* kx    = (const float*)d_in[0];
    const float* pos   = (const float*)d_in[1];
    const float* mask  = (const float*)d_in[2];
    const float* scale = (const float*)d_in[3];
    const float* ev    = (const float*)d_in[4];
    const float* Wx    = (const float*)d_in[5];
    const float* bx    = (const float*)d_in[6];
    const float* Wk    = (const float*)d_in[7];
    const float* bk    = (const float*)d_in[8];
    float* out = (float*)d_out;
    unsigned short* ws = (unsigned short*)d_ws;

    // W hi/lo split (128KB at ws[0]) — needed by both paths
    hipLaunchKernelGGL(wsplit_kernel, dim3(128), dim3(256), 0, stream, Wx, Wk, ws);

    const size_t need = 131072 + 2 * (size_t)NBATCH * NATOM * EDIM * 2;  // W + X + K
    if (ws_size >= need) {
        (void)hipFuncSetAttribute((const void*)k1_act_gemm,
                                  hipFuncAttributeMaxDynamicSharedMemorySize, 65536);
        hipLaunchKernelGGL(k1_act_gemm, dim3(NBATCH), dim3(512), 65536, stream,
                           kx, mask, bx, bk, ws);
        hipLaunchKernelGGL(k2_gram_epi, dim3(NBATCH), dim3(512), 0, stream,
                           kx, pos, mask, scale, ev, ws, out);
    } else {
        (void)hipFuncSetAttribute((const void*)gen_actions_fallback,
                                  hipFuncAttributeMaxDynamicSharedMemorySize, 2 * PLANE_SZ);
        hipLaunchKernelGGL(gen_actions_fallback, dim3(NBATCH / 2), dim3(1024),
                           2 * PLANE_SZ, stream,
                           kx, pos, mask, scale, ev, bx, bk, ws, out);
    }
}

// Round 8
// 67.740 us; speedup vs baseline: 1.3712x; 1.3712x over previous
//
#include <hip/hip_runtime.h>
#include <math.h>

#define EDIM 128
#define NATOM 128
#define NBATCH 512
#define THREADS 1024
#define ROWLEN 257

typedef __attribute__((ext_vector_type(8))) short bf16x8;           // 8 bf16 (4 VGPRs)
typedef __attribute__((ext_vector_type(4))) float f32x4;            // MFMA C/D frag
typedef __attribute__((ext_vector_type(4))) unsigned short u16x4;   // 8B packed bf16
typedef float f4u __attribute__((ext_vector_type(4), aligned(4)));  // element-aligned float4

__device__ __forceinline__ unsigned short f2bf(float f) {       // RNE float->bf16 (host-side helper kernel)
    unsigned u = __float_as_uint(f);
    u += 0x7FFFu + ((u >> 16) & 1u);
    return (unsigned short)(u >> 16);
}
__device__ __forceinline__ float bf2f(unsigned short h) {
    return __uint_as_float(((unsigned)h) << 16);
}
// 1-op RNE f32->bf16 via HW pack convert (src0==src1 -> order-immune)
__device__ __forceinline__ unsigned short cvt1(float x) {
    unsigned r;
    asm("v_cvt_pk_bf16_f32 %0, %1, %1" : "=v"(r) : "v"(x));
    return (unsigned short)r;
}
__device__ __forceinline__ float fast_ssp(float x) {            // softplus(x)-log2, stable
    return fmaxf(x, 0.f) + __logf(1.f + __expf(-fabsf(x))) - 0.69314718055994531f;
}
// XOR swizzle on a row-major [128][256B] bf16 plane; phase decorrelates X vs K plane.
// Operates on byte bits 4..6 only -> consistent for b16 scalar and b128 accesses.
__device__ __forceinline__ int swzp(int row, int cbyte, int phase) {
    return row * 256 + ((cbyte ^ phase) ^ ((row & 7) << 4));
}

#define PH 0
#define QH 32768

__global__ void wsplit_kernel(const float* __restrict__ Wx,
                              const float* __restrict__ Wk,
                              unsigned short* __restrict__ ws) {
    int g = blockIdx.x * 256 + threadIdx.x;          // 0..32767
    const float* src = (g < 16384) ? Wx : Wk;
    int idx = g & 16383;
    float v = src[idx];
    unsigned short h = f2bf(v);
    unsigned short l = f2bf(v - bf2f(h));
    int base = (g < 16384) ? 0 : 32768;
    ws[base + idx] = h;
    ws[base + 16384 + idx] = l;
}

__global__ void __launch_bounds__(THREADS, 4)   // VGPR cap 128, 1 block/CU (16 waves)
gen_actions_kernel(const float* __restrict__ kx,
                   const float* __restrict__ pos,
                   const float* __restrict__ mask,
                   const float* __restrict__ scale_ptr,
                   const float* __restrict__ evala,
                   const float* __restrict__ bx,
                   const float* __restrict__ bk,
                   const unsigned short* __restrict__ ws,
                   float* __restrict__ out)
{
    extern __shared__ char lds[];        // act_x/X plane (32KB) + act_k/K plane (32KB)
    __shared__ float posXs[NATOM], posYs[NATOM], posZs[NATOM], lsBs[NATOM];
    __shared__ float amBs[NATOM * 3];
    __shared__ float redBs[2];
    __shared__ int   cntBs[2];

    const int b = blockIdx.x;
    const int t = threadIdx.x;
    const int lane = t & 63;
    const int w = t >> 6;            // wave 0..15
    const int wr = w >> 2;           // M tile (features / atoms-i), 0..3
    const int wc = w & 3;            // N tile (atoms-j), 0..3
    const int l15 = lane & 15;
    const int l4  = lane >> 4;

    // ---------------- P1: count, positions, log_std, zero accumulators
    if (t < NATOM) {
        float m = mask[b * NATOM + t];
        unsigned long long bal = __ballot(m > 0.5f);
        if ((t & 63) == 0) cntBs[t >> 6] = __popcll(bal);
        const float* p = pos + ((size_t)b * NATOM + t) * 3;
        posXs[t] = p[0]; posYs[t] = p[1]; posZs[t] = p[2];
        lsBs[t] = kx[(size_t)b * (NATOM * ROWLEN) + t * ROWLEN + 2 * EDIM];
    }
    if (t < NATOM * 3) amBs[t] = 0.f;

    // ---------------- P2: coalesced kx stream -> bf16 activation planes.
    // Wave = one half-row (128 floats): lane reads scalars at row*1028B + (lane, lane+64)*4B
    // -> each load instr is a 256B fully-contiguous segment. j<8: softplus halves (cols
    // 0..127); j>=8: relu halves (cols 128..255). Branch is compile-time wave-uniform.
    // No masking: masked-row garbage is finite and killed downstream (guards/gates).
    {
        const float* kb = kx + (size_t)b * (NATOM * ROWLEN);
        #pragma unroll
        for (int j = 0; j < 16; ++j) {
            const int row = (j * 16 + w) & 127;
            const bool isX = (j < 8);
            const float* src = kb + row * ROWLEN + (isX ? 0 : 128);
            float x0 = src[lane];
            float x1 = src[lane + 64];
            float a0 = isX ? fast_ssp(x0) : fmaxf(x0, 0.f);
            float a1 = isX ? fast_ssp(x1) : fmaxf(x1, 0.f);
            char* base = lds + (isX ? PH : QH);
            const int phase = isX ? 0 : 64;
            *(unsigned short*)(base + swzp(row, lane * 2, phase)) = cvt1(a0);
            *(unsigned short*)(base + swzp(row, (lane + 64) * 2, phase)) = cvt1(a1);
        }
    }
    __syncthreads();                 // B1: planes + count + pos ready
    const int count = cntBs[0] + cntBs[1];   // mask is a contiguous prefix

    // ---------------- P3 (merged): X and K GEMMs in one compute phase.
    // X = act @ W^T + b as D[feature][atom]; W hi/lo split (d_ws, L2-hot) for ~fp32 acc.
    const int n0 = wc * 32;                    // atom tile base (N-dim)
    const bool nact = (n0 < count);
    u16x4 xpk[2][2], kpk[2][2];
    if (nact) {
        #pragma unroll
        for (int mat = 0; mat < 2; ++mat) {
            const char* act = lds + (mat ? QH : PH);
            const int phase = mat ? 64 : 0;
            const unsigned short* WH = ws + mat * 32768;
            const unsigned short* WL = WH + 16384;
            const float* bias = mat ? bk : bx;
            f32x4 acc[2][2] = {};
            for (int ks = 0; ks < 4; ++ks) {
                const int e0 = ks * 32 + l4 * 8;   // k-offset for this lane
                bf16x8 wh[2], wl[2], ah[2];
                #pragma unroll
                for (int mf = 0; mf < 2; ++mf) {
                    int orow = wr * 32 + mf * 16 + l15;
                    wh[mf] = *(const bf16x8*)(WH + orow * 128 + e0);
                    wl[mf] = *(const bf16x8*)(WL + orow * 128 + e0);
                }
                #pragma unroll
                for (int nf = 0; nf < 2; ++nf) {
                    int jrow = n0 + nf * 16 + l15;
                    ah[nf] = *(const bf16x8*)(act + swzp(jrow, e0 * 2, phase));
                }
                #pragma unroll
                for (int mf = 0; mf < 2; ++mf)
                    #pragma unroll
                    for (int nf = 0; nf < 2; ++nf) {
                        acc[mf][nf] = __builtin_amdgcn_mfma_f32_16x16x32_bf16(wh[mf], ah[nf], acc[mf][nf], 0, 0, 0);
                        acc[mf][nf] = __builtin_amdgcn_mfma_f32_16x16x32_bf16(wl[mf], ah[nf], acc[mf][nf], 0, 0, 0);
                    }
            }
            #pragma unroll
            for (int mf = 0; mf < 2; ++mf) {
                int ob = wr * 32 + mf * 16 + l4 * 4;
                f32x4 b4 = *(const f32x4*)(bias + ob);
                #pragma unroll
                for (int nf = 0; nf < 2; ++nf) {
                    u16x4 hs;
                    #pragma unroll
                    for (int r = 0; r < 4; ++r) hs[r] = cvt1(acc[mf][nf][r] + b4[r]);
                    if (mat) kpk[mf][nf] = hs; else xpk[mf][nf] = hs;
                }
            }
        }
    }
    __syncthreads();                 // B2: all activation-plane reads complete
    if (nact) {
        #pragma unroll
        for (int mf = 0; mf < 2; ++mf) {
            int ob2 = (wr * 32 + mf * 16 + l4 * 4) * 2;
            #pragma unroll
            for (int nf = 0; nf < 2; ++nf) {
                int jrow = n0 + nf * 16 + l15;               // atom (D col)
                *(u16x4*)(lds + PH + swzp(jrow, ob2, 0))  = xpk[mf][nf];
                *(u16x4*)(lds + QH + swzp(jrow, ob2, 64)) = kpk[mf][nf];
            }
        }
    }
    __syncthreads();                 // B3: X,K planes ready

    // ---------------- P4: Grams G = X@X^T, K@K^T (bf16) + pairwise epilogue
    const int m0g = wr * 32;       // i tile base
    const int n0g = wc * 32;       // j tile base
    f32x4 gx[2][2] = {}, gk[2][2] = {};
    const bool active = (m0g < count) && (n0g < count);
    if (active) {
        for (int ks = 0; ks < 4; ++ks) {           // X gram
            const int e0b = (ks * 32 + l4 * 8) * 2;
            bf16x8 aH[2], bH[2];
            #pragma unroll
            for (int mf = 0; mf < 2; ++mf)
                aH[mf] = *(const bf16x8*)(lds + PH + swzp(m0g + mf * 16 + l15, e0b, 0));
            #pragma unroll
            for (int nf = 0; nf < 2; ++nf)
                bH[nf] = *(const bf16x8*)(lds + PH + swzp(n0g + nf * 16 + l15, e0b, 0));
            #pragma unroll
            for (int mf = 0; mf < 2; ++mf)
                #pragma unroll
                for (int nf = 0; nf < 2; ++nf)
                    gx[mf][nf] = __builtin_amdgcn_mfma_f32_16x16x32_bf16(aH[mf], bH[nf], gx[mf][nf], 0, 0, 0);
        }
        for (int ks = 0; ks < 4; ++ks) {           // K gram
            const int e0b = (ks * 32 + l4 * 8) * 2;
            bf16x8 aH[2], bH[2];
            #pragma unroll
            for (int mf = 0; mf < 2; ++mf)
                aH[mf] = *(const bf16x8*)(lds + QH + swzp(m0g + mf * 16 + l15, e0b, 64));
            #pragma unroll
            for (int nf = 0; nf < 2; ++nf)
                bH[nf] = *(const bf16x8*)(lds + QH + swzp(n0g + nf * 16 + l15, e0b, 64));
            #pragma unroll
            for (int mf = 0; mf < 2; ++mf)
                #pragma unroll
                for (int nf = 0; nf < 2; ++nf)
                    gk[mf][nf] = __builtin_amdgcn_mfma_f32_16x16x32_bf16(aH[mf], bH[nf], gk[mf][nf], 0, 0, 0);
        }
        // pairwise epilogue on D-frags: lane's column j fixed per nf
        const float inv_e = 0.08838834764831845f;            // 1/sqrt(128)
        #pragma unroll
        for (int nf = 0; nf < 2; ++nf) {
            const int j = n0g + nf * 16 + l15;
            const bool jvalid = (j < count);
            const float pjx = posXs[j], pjy = posYs[j], pjz = posZs[j];
            float amx = 0.f, amy = 0.f, amz = 0.f;
            #pragma unroll
            for (int mf = 0; mf < 2; ++mf) {
                #pragma unroll
                for (int r = 0; r < 4; ++r) {
                    const int i = m0g + mf * 16 + l4 * 4 + r;
                    float dx = pjx - posXs[i];
                    float dy = pjy - posYs[i];
                    float dz = pjz - posZs[i];
                    float r2 = fmaf(dx, dx, fmaf(dy, dy, dz * dz)) + 1e-16f;
                    float rr = sqrtf(r2);
                    bool ok = jvalid && (i < count) && (rr < 5.0f);
                    float fc = ok ? (0.5f * (__cosf(rr * 0.62831853071795865f) + 1.f)) : 0.f;
                    float xs = fmaf(gx[mf][nf][r], -0.044194173824159216f, rr * 0.5f);
                    float fv = xs * (gk[mf][nf][r] * inv_e) * fc;
                    float wgt = fv / (rr + 1e-8f);
                    amx = fmaf(dx, wgt, amx);
                    amy = fmaf(dy, wgt, amy);
                    amz = fmaf(dz, wgt, amz);
                }
            }
            amx += __shfl_xor(amx, 16); amx += __shfl_xor(amx, 32);
            amy += __shfl_xor(amy, 16); amy += __shfl_xor(amy, 32);
            amz += __shfl_xor(amz, 16); amz += __shfl_xor(amz, 32);
            if (l4 == 0 && jvalid) {
                atomicAdd(&amBs[j * 3 + 0], amx);
                atomicAdd(&amBs[j * 3 + 1], amy);
                atomicAdd(&amBs[j * 3 + 2], amz);
            }
        }
    }
    __syncthreads();                 // B4: actions_mean complete

    // ---------------- P5: outputs
    if (t < 96) {
        f32x4 ev4 = *(const f32x4*)(evala + (size_t)b * 384 + t * 4);
        f32x4 o4;
        #pragma unroll
        for (int c = 0; c < 4; ++c) {
            int atom = (t * 4 + c) / 3;
            o4[c] = (atom < count) ? ev4[c] : 0.f;
        }
        *(f32x4*)(out + (size_t)b * 384 + t * 4) = o4;
    }
    float lp = 0.f;
    if (t < NATOM && t < count) {
        const float* ev = evala + ((size_t)b * NATOM + t) * 3;
        float e0v = ev[0], e1v = ev[1], e2v = ev[2];
        float scale = scale_ptr[0];
        float ax = amBs[t * 3 + 0], ay = amBs[t * 3 + 1], az = amBs[t * 3 + 2];
        float nrm = sqrtf(fmaf(ax, ax, fmaf(ay, ay, az * az)) + 1e-16f) + 1e-8f;
        float qe = __expf(-2.f * nrm);
        float th = (1.f - qe) / (1.f + qe);
        float sc = th / nrm * scale;
        float ls = fminf(fmaxf(lsBs[t], -20.f), 2.f);
        float sig = __expf(ls) * scale;
        float sinv = 1.f / sig;
        float zx = (e0v - ax * sc) * sinv;
        float zy = (e1v - ay * sc) * sinv;
        float zz = (e2v - az * sc) * sinv;
        lp = -0.5f * (zx * zx + zy * zy + zz * zz) - 3.f * __logf(sig)
             - 3.f * 0.91893853320467274f;
    }
    #pragma unroll
    for (int off = 32; off > 0; off >>= 1) lp += __shfl_down(lp, off);
    if (t == 0)  redBs[0] = lp;
    if (t == 64) redBs[1] = lp;
    __syncthreads();                 // B5
    if (t == 0) out[(size_t)NBATCH * NATOM * 3 + b] = redBs[0] + redBs[1];
}

extern "C" void kernel_launch(void* const* d_in, const int* in_sizes, int n_in,
                              void* d_out, int out_size, void* d_ws, size_t ws_size,
                              hipStream_t stream) {
    const float* kx    = (const float*)d_in[0];
    const float* pos   = (const float*)d_in[1];
    const float* mask  = (const float*)d_in[2];
    const float* scale = (const float*)d_in[3];
    const float* ev    = (const float*)d_in[4];
    const float* Wx    = (const float*)d_in[5];
    const float* bx    = (const float*)d_in[6];
    const float* Wk    = (const float*)d_in[7];
    const float* bk    = (const float*)d_in[8];
    float* out = (float*)d_out;
    unsigned short* ws = (unsigned short*)d_ws;

    // W hi/lo split (128KB in d_ws), recomputed each launch (deterministic)
    hipLaunchKernelGGL(wsplit_kernel, dim3(128), dim3(256), 0, stream, Wx, Wk, ws);

    const size_t shbytes = 65536;   // 2 planes x 32KB dynamic LDS
    (void)hipFuncSetAttribute((const void*)gen_actions_kernel,
                              hipFuncAttributeMaxDynamicSharedMemorySize,
                              (int)shbytes);
    hipLaunchKernelGGL(gen_actions_kernel, dim3(NBATCH), dim3(THREADS), shbytes, stream,
                       kx, pos, mask, scale, ev, bx, bk, ws, out);
}